// Round 1
// baseline (214.449 us; speedup 1.0000x reference)
//
#include <hip/hip_runtime.h>

// VDR (Student-t kernel MMD variance) — fused one-pass.
// sum((K - rm - cm + t)^2) == sum(K^2) - sum(rowsum^2)/n - sum(colsum^2)/m + T^2/(mn)
// so we never materialize K. Gram via f16 MFMA (error analysis: delta on final
// scalar < 1e-8 vs tolerance 7.4e-6). Diagonal of K_XX/K_YY forced to GAMMA
// (exact, since ref's d2_ii = -2*XX_ii + XX_ii + XX_ii = 0 identically).

typedef __attribute__((ext_vector_type(8))) _Float16 f16x8;
typedef __attribute__((ext_vector_type(2))) _Float16 f16x2;
typedef __attribute__((ext_vector_type(4))) float f32x4;

#define N4096 4096
#define GAMMA_F 0.50241665f   // gamma(0.8)/(gamma(0.3)*sqrt(0.6))

// workspace layout (bytes)
#define OFF_S2      0         // double S2[4] (3 used)
#define OFF_ROWSUM  32        // float rowsum[3][4096]
#define OFF_COLSUM  49184     // float colsum[3][4096]
#define OFF_SQ1     98336     // float sq1[4096]
#define OFF_SQ2     114720    // float sq2[4096]
#define OFF_H1      131104    // _Float16 H1[4096*128]
#define OFF_H2      1179680   // _Float16 H2[4096*128]
#define ZERO_BYTES  98336

// ---- prep: fp32 -> f16 convert + squared row norms (one wave per row) ----
__global__ __launch_bounds__(256) void vdr_prep(const float* __restrict__ X1,
                                                const float* __restrict__ X2,
                                                _Float16* __restrict__ H1,
                                                _Float16* __restrict__ H2,
                                                float* __restrict__ sq1,
                                                float* __restrict__ sq2) {
  const int gw = (blockIdx.x * 256 + threadIdx.x) >> 6;  // global wave = row over [0, 8192)
  const int lane = threadIdx.x & 63;
  const float* X; _Float16* H; float* SQ; int row;
  if (gw < N4096) { X = X1; H = H1; SQ = sq1; row = gw; }
  else            { X = X2; H = H2; SQ = sq2; row = gw - N4096; }
  const float2 v = reinterpret_cast<const float2*>(X + (size_t)row * 128)[lane];
  f16x2 h; h.x = (_Float16)v.x; h.y = (_Float16)v.y;
  reinterpret_cast<f16x2*>(H + (size_t)row * 128)[lane] = h;
  float s = v.x * v.x + v.y * v.y;
  #pragma unroll
  for (int o = 32; o; o >>= 1) s += __shfl_xor(s, o);
  if (lane == 0) SQ[row] = s;
}

// ---- main: per 128x128 tile of one of {XX, XY, YY}: MFMA gram -> K -> sums ----
__global__ __launch_bounds__(256) void vdr_main(const _Float16* __restrict__ H1,
                                                const _Float16* __restrict__ H2,
                                                const float* __restrict__ sq1,
                                                const float* __restrict__ sq2,
                                                float* __restrict__ rowsum,
                                                float* __restrict__ colsum,
                                                double* __restrict__ S2) {
  const int z = blockIdx.z;                       // 0:XX 1:XY 2:YY
  const _Float16* Ap = (z == 2) ? H2 : H1;
  const _Float16* Bp = (z == 0) ? H1 : H2;
  const float* asq = (z == 2) ? sq2 : sq1;
  const float* bsq = (z == 0) ? sq1 : sq2;
  const bool diag = (z != 1);

  const int w = threadIdx.x >> 6;
  const int lane = threadIdx.x & 63;
  const int lr = lane & 15, lg = lane >> 4;
  const int row0 = blockIdx.x * 128 + (w >> 1) * 64;   // wave's 64x64 sub-tile
  const int col0 = blockIdx.y * 128 + (w & 1) * 64;

  f32x4 acc[4][4];
  #pragma unroll
  for (int mi = 0; mi < 4; ++mi)
    #pragma unroll
    for (int ni = 0; ni < 4; ++ni)
      acc[mi][ni] = (f32x4){0.f, 0.f, 0.f, 0.f};

  // A frag (16x16x32 f16): row = lane%16, k = 8*(lane/16)+e ; B mirrors with col = lane%16.
  #pragma unroll
  for (int ks = 0; ks < 4; ++ks) {
    const int ko = ks * 32 + lg * 8;
    f16x8 a[4], b[4];
    #pragma unroll
    for (int mi = 0; mi < 4; ++mi)
      a[mi] = *reinterpret_cast<const f16x8*>(Ap + (size_t)(row0 + mi * 16 + lr) * 128 + ko);
    #pragma unroll
    for (int ni = 0; ni < 4; ++ni)
      b[ni] = *reinterpret_cast<const f16x8*>(Bp + (size_t)(col0 + ni * 16 + lr) * 128 + ko);
    #pragma unroll
    for (int mi = 0; mi < 4; ++mi)
      #pragma unroll
      for (int ni = 0; ni < 4; ++ni)
        acc[mi][ni] = __builtin_amdgcn_mfma_f32_16x16x32_f16(a[mi], b[ni], acc[mi][ni], 0, 0, 0);
  }

  float bsqc[4];
  #pragma unroll
  for (int ni = 0; ni < 4; ++ni) bsqc[ni] = bsq[col0 + ni * 16 + lr];

  float k2s = 0.f;
  float cpart[4] = {0.f, 0.f, 0.f, 0.f};

  // C/D layout: col = lane&15, row = (lane>>4)*4 + reg   [m89/m91 verified]
  #pragma unroll
  for (int mi = 0; mi < 4; ++mi) {
    #pragma unroll
    for (int reg = 0; reg < 4; ++reg) {
      const int grow = row0 + mi * 16 + lg * 4 + reg;
      const float asr = asq[grow];
      float rp = 0.f;
      #pragma unroll
      for (int ni = 0; ni < 4; ++ni) {
        const int gcol = col0 + ni * 16 + lr;
        const float G = acc[mi][ni][reg];
        float Kv;
        if (diag && grow == gcol) {
          Kv = GAMMA_F;                                   // d2 == 0 exactly in ref
        } else {
          const float base = 1.0f + 0.5f * (asr + bsqc[ni] - 2.0f * G);
          Kv = GAMMA_F * __builtin_amdgcn_exp2f(-0.8f * __builtin_amdgcn_logf(base));
        }
        rp += Kv;
        cpart[ni] += Kv;
        k2s += Kv * Kv;
      }
      // rows live on lanes sharing lg: reduce across the 16-lane (lr) group
      #pragma unroll
      for (int o = 1; o < 16; o <<= 1) rp += __shfl_xor(rp, o);
      if (lr == 0) unsafeAtomicAdd(&rowsum[z * N4096 + grow], rp);
    }
  }
  #pragma unroll
  for (int ni = 0; ni < 4; ++ni) {
    float cp = cpart[ni];
    cp += __shfl_xor(cp, 16);
    cp += __shfl_xor(cp, 32);
    if (lg == 0) unsafeAtomicAdd(&colsum[z * N4096 + col0 + ni * 16 + lr], cp);
  }
  #pragma unroll
  for (int o = 32; o; o >>= 1) k2s += __shfl_xor(k2s, o);
  if (lane == 0) unsafeAtomicAdd(&S2[z], (double)k2s);
}

// ---- final: combine in f64 ----
__global__ __launch_bounds__(256) void vdr_final(const float* __restrict__ rowsum,
                                                 const float* __restrict__ colsum,
                                                 const double* __restrict__ S2,
                                                 float* __restrict__ out) {
  __shared__ double shr[4], shc[4], sht[4];
  __shared__ double res[3];
  const int tid = threadIdx.x;
  const int lane = tid & 63, wid = tid >> 6;
  for (int mat = 0; mat < 3; ++mat) {
    double sr = 0.0, sc = 0.0, t = 0.0;
    for (int i = tid; i < N4096; i += 256) {
      const double r = (double)rowsum[mat * N4096 + i];
      const double c = (double)colsum[mat * N4096 + i];
      sr += r * r; sc += c * c; t += r;
    }
    #pragma unroll
    for (int o = 32; o; o >>= 1) {
      sr += __shfl_down(sr, o);
      sc += __shfl_down(sc, o);
      t  += __shfl_down(t, o);
    }
    if (lane == 0) { shr[wid] = sr; shc[wid] = sc; sht[wid] = t; }
    __syncthreads();
    if (tid == 0) {
      const double SR = shr[0] + shr[1] + shr[2] + shr[3];
      const double SC = shc[0] + shc[1] + shc[2] + shc[3];
      const double T  = sht[0] + sht[1] + sht[2] + sht[3];
      const double inv = 1.0 / 4096.0;
      res[mat] = S2[mat] - SR * inv - SC * inv + T * T * inv * inv;
    }
    __syncthreads();
  }
  if (tid == 0) {
    const double mf = 4096.0;
    const double vdr2 = (res[0] - mf) / ((mf - 1.0) * mf)
                      + (res[2] - mf) / ((mf - 1.0) * mf)
                      - 2.0 * res[1] / (mf * mf);
    out[0] = (float)vdr2;
  }
}

extern "C" void kernel_launch(void* const* d_in, const int* in_sizes, int n_in,
                              void* d_out, int out_size, void* d_ws, size_t ws_size,
                              hipStream_t stream) {
  const float* X1 = (const float*)d_in[0];
  const float* X2 = (const float*)d_in[1];
  char* ws = (char*)d_ws;
  double* S2      = (double*)(ws + OFF_S2);
  float* rowsum   = (float*)(ws + OFF_ROWSUM);
  float* colsum   = (float*)(ws + OFF_COLSUM);
  float* sq1      = (float*)(ws + OFF_SQ1);
  float* sq2      = (float*)(ws + OFF_SQ2);
  _Float16* H1    = (_Float16*)(ws + OFF_H1);
  _Float16* H2    = (_Float16*)(ws + OFF_H2);

  hipMemsetAsync(d_ws, 0, ZERO_BYTES, stream);
  vdr_prep<<<2048, 256, 0, stream>>>(X1, X2, H1, H2, sq1, sq2);
  dim3 grid(32, 32, 3);
  vdr_main<<<grid, 256, 0, stream>>>(H1, H2, sq1, sq2, rowsum, colsum, S2);
  vdr_final<<<1, 256, 0, stream>>>(rowsum, colsum, S2, (float*)d_out);
}

// Round 2
// 121.053 us; speedup vs baseline: 1.7715x; 1.7715x over previous
//
#include <hip/hip_runtime.h>

// VDR (Student-t kernel MMD variance) — fused one-pass.
// sum((K - rm - cm + t)^2) == sum(K^2) - sum(rowsum^2)/n - sum(colsum^2)/m + T^2/(mn)
// Gram via f16 MFMA. Diagonal of K_XX/K_YY forced to GAMMA (exact in ref).
// R1 fix: S2 was a single-cacheline atomic hot spot (12288 f64 atomics onto 3
// adjacent doubles -> ~190us serialization). Replaced with per-block partial
// stores (bpart[3][1024]) reduced in vdr_final.

typedef __attribute__((ext_vector_type(8))) _Float16 f16x8;
typedef __attribute__((ext_vector_type(2))) _Float16 f16x2;
typedef __attribute__((ext_vector_type(4))) float f32x4;

#define N4096 4096
#define GAMMA_F 0.50241665f   // gamma(0.8)/(gamma(0.3)*sqrt(0.6))

// workspace layout (bytes)
#define OFF_ROWSUM  32        // float rowsum[3][4096]
#define OFF_COLSUM  49184     // float colsum[3][4096]
#define OFF_SQ1     98336     // float sq1[4096]
#define OFF_SQ2     114720    // float sq2[4096]
#define OFF_H1      131104    // _Float16 H1[4096*128]
#define OFF_H2      1179680   // _Float16 H2[4096*128]
#define OFF_BPART   2228256   // float bpart[3][1024]
#define ZERO_BYTES  98336     // rowsum+colsum must start at 0 (atomic accum)

// ---- prep: fp32 -> f16 convert + squared row norms (one wave per row) ----
__global__ __launch_bounds__(256) void vdr_prep(const float* __restrict__ X1,
                                                const float* __restrict__ X2,
                                                _Float16* __restrict__ H1,
                                                _Float16* __restrict__ H2,
                                                float* __restrict__ sq1,
                                                float* __restrict__ sq2) {
  const int gw = (blockIdx.x * 256 + threadIdx.x) >> 6;  // global wave = row over [0, 8192)
  const int lane = threadIdx.x & 63;
  const float* X; _Float16* H; float* SQ; int row;
  if (gw < N4096) { X = X1; H = H1; SQ = sq1; row = gw; }
  else            { X = X2; H = H2; SQ = sq2; row = gw - N4096; }
  const float2 v = reinterpret_cast<const float2*>(X + (size_t)row * 128)[lane];
  f16x2 h; h.x = (_Float16)v.x; h.y = (_Float16)v.y;
  reinterpret_cast<f16x2*>(H + (size_t)row * 128)[lane] = h;
  float s = v.x * v.x + v.y * v.y;
  #pragma unroll
  for (int o = 32; o; o >>= 1) s += __shfl_xor(s, o);
  if (lane == 0) SQ[row] = s;
}

// ---- main: per 128x128 tile of one of {XX, XY, YY}: MFMA gram -> K -> sums ----
__global__ __launch_bounds__(256) void vdr_main(const _Float16* __restrict__ H1,
                                                const _Float16* __restrict__ H2,
                                                const float* __restrict__ sq1,
                                                const float* __restrict__ sq2,
                                                float* __restrict__ rowsum,
                                                float* __restrict__ colsum,
                                                float* __restrict__ bpart) {
  const int z = blockIdx.z;                       // 0:XX 1:XY 2:YY
  const _Float16* Ap = (z == 2) ? H2 : H1;
  const _Float16* Bp = (z == 0) ? H1 : H2;
  const float* asq = (z == 2) ? sq2 : sq1;
  const float* bsq = (z == 0) ? sq1 : sq2;
  const bool diag = (z != 1);

  const int w = threadIdx.x >> 6;
  const int lane = threadIdx.x & 63;
  const int lr = lane & 15, lg = lane >> 4;
  const int row0 = blockIdx.x * 128 + (w >> 1) * 64;   // wave's 64x64 sub-tile
  const int col0 = blockIdx.y * 128 + (w & 1) * 64;

  f32x4 acc[4][4];
  #pragma unroll
  for (int mi = 0; mi < 4; ++mi)
    #pragma unroll
    for (int ni = 0; ni < 4; ++ni)
      acc[mi][ni] = (f32x4){0.f, 0.f, 0.f, 0.f};

  // A frag (16x16x32 f16): row = lane%16, k = 8*(lane/16)+e ; B mirrors with col = lane%16.
  #pragma unroll
  for (int ks = 0; ks < 4; ++ks) {
    const int ko = ks * 32 + lg * 8;
    f16x8 a[4], b[4];
    #pragma unroll
    for (int mi = 0; mi < 4; ++mi)
      a[mi] = *reinterpret_cast<const f16x8*>(Ap + (size_t)(row0 + mi * 16 + lr) * 128 + ko);
    #pragma unroll
    for (int ni = 0; ni < 4; ++ni)
      b[ni] = *reinterpret_cast<const f16x8*>(Bp + (size_t)(col0 + ni * 16 + lr) * 128 + ko);
    #pragma unroll
    for (int mi = 0; mi < 4; ++mi)
      #pragma unroll
      for (int ni = 0; ni < 4; ++ni)
        acc[mi][ni] = __builtin_amdgcn_mfma_f32_16x16x32_f16(a[mi], b[ni], acc[mi][ni], 0, 0, 0);
  }

  float bsqc[4];
  #pragma unroll
  for (int ni = 0; ni < 4; ++ni) bsqc[ni] = bsq[col0 + ni * 16 + lr];

  float k2s = 0.f;
  float cpart[4] = {0.f, 0.f, 0.f, 0.f};

  // C/D layout: col = lane&15, row = (lane>>4)*4 + reg   [m89/m91 verified]
  #pragma unroll
  for (int mi = 0; mi < 4; ++mi) {
    #pragma unroll
    for (int reg = 0; reg < 4; ++reg) {
      const int grow = row0 + mi * 16 + lg * 4 + reg;
      const float asr = asq[grow];
      float rp = 0.f;
      #pragma unroll
      for (int ni = 0; ni < 4; ++ni) {
        const int gcol = col0 + ni * 16 + lr;
        const float G = acc[mi][ni][reg];
        float Kv;
        if (diag && grow == gcol) {
          Kv = GAMMA_F;                                   // d2 == 0 exactly in ref
        } else {
          const float base = 1.0f + 0.5f * (asr + bsqc[ni] - 2.0f * G);
          Kv = GAMMA_F * __builtin_amdgcn_exp2f(-0.8f * __builtin_amdgcn_logf(base));
        }
        rp += Kv;
        cpart[ni] += Kv;
        k2s += Kv * Kv;
      }
      // rows live on lanes sharing lg: reduce across the 16-lane (lr) group
      #pragma unroll
      for (int o = 1; o < 16; o <<= 1) rp += __shfl_xor(rp, o);
      if (lr == 0) unsafeAtomicAdd(&rowsum[z * N4096 + grow], rp);
    }
  }
  #pragma unroll
  for (int ni = 0; ni < 4; ++ni) {
    float cp = cpart[ni];
    cp += __shfl_xor(cp, 16);
    cp += __shfl_xor(cp, 32);
    if (lg == 0) unsafeAtomicAdd(&colsum[z * N4096 + col0 + ni * 16 + lr], cp);
  }
  #pragma unroll
  for (int o = 32; o; o >>= 1) k2s += __shfl_xor(k2s, o);

  // block-level reduce (4 waves) -> single per-block partial store, NO atomic
  __shared__ float sred[4];
  if (lane == 0) sred[w] = k2s;
  __syncthreads();
  if (threadIdx.x == 0)
    bpart[z * 1024 + blockIdx.y * 32 + blockIdx.x] =
        sred[0] + sred[1] + sred[2] + sred[3];
}

// ---- final: combine in f64 ----
__global__ __launch_bounds__(256) void vdr_final(const float* __restrict__ rowsum,
                                                 const float* __restrict__ colsum,
                                                 const float* __restrict__ bpart,
                                                 float* __restrict__ out) {
  __shared__ double shr[4], shc[4], sht[4], shs[4];
  __shared__ double res[3];
  const int tid = threadIdx.x;
  const int lane = tid & 63, wid = tid >> 6;
  for (int mat = 0; mat < 3; ++mat) {
    double sr = 0.0, sc = 0.0, t = 0.0, s2 = 0.0;
    for (int i = tid; i < N4096; i += 256) {
      const double r = (double)rowsum[mat * N4096 + i];
      const double c = (double)colsum[mat * N4096 + i];
      sr += r * r; sc += c * c; t += r;
    }
    for (int i = tid; i < 1024; i += 256)
      s2 += (double)bpart[mat * 1024 + i];
    #pragma unroll
    for (int o = 32; o; o >>= 1) {
      sr += __shfl_down(sr, o);
      sc += __shfl_down(sc, o);
      t  += __shfl_down(t, o);
      s2 += __shfl_down(s2, o);
    }
    if (lane == 0) { shr[wid] = sr; shc[wid] = sc; sht[wid] = t; shs[wid] = s2; }
    __syncthreads();
    if (tid == 0) {
      const double SR = shr[0] + shr[1] + shr[2] + shr[3];
      const double SC = shc[0] + shc[1] + shc[2] + shc[3];
      const double T  = sht[0] + sht[1] + sht[2] + sht[3];
      const double S2 = shs[0] + shs[1] + shs[2] + shs[3];
      const double inv = 1.0 / 4096.0;
      res[mat] = S2 - SR * inv - SC * inv + T * T * inv * inv;
    }
    __syncthreads();
  }
  if (tid == 0) {
    const double mf = 4096.0;
    const double vdr2 = (res[0] - mf) / ((mf - 1.0) * mf)
                      + (res[2] - mf) / ((mf - 1.0) * mf)
                      - 2.0 * res[1] / (mf * mf);
    out[0] = (float)vdr2;
  }
}

extern "C" void kernel_launch(void* const* d_in, const int* in_sizes, int n_in,
                              void* d_out, int out_size, void* d_ws, size_t ws_size,
                              hipStream_t stream) {
  const float* X1 = (const float*)d_in[0];
  const float* X2 = (const float*)d_in[1];
  char* ws = (char*)d_ws;
  float* rowsum   = (float*)(ws + OFF_ROWSUM);
  float* colsum   = (float*)(ws + OFF_COLSUM);
  float* sq1      = (float*)(ws + OFF_SQ1);
  float* sq2      = (float*)(ws + OFF_SQ2);
  _Float16* H1    = (_Float16*)(ws + OFF_H1);
  _Float16* H2    = (_Float16*)(ws + OFF_H2);
  float* bpart    = (float*)(ws + OFF_BPART);

  hipMemsetAsync(d_ws, 0, ZERO_BYTES, stream);
  vdr_prep<<<2048, 256, 0, stream>>>(X1, X2, H1, H2, sq1, sq2);
  dim3 grid(32, 32, 3);
  vdr_main<<<grid, 256, 0, stream>>>(H1, H2, sq1, sq2, rowsum, colsum, bpart);
  vdr_final<<<1, 256, 0, stream>>>(rowsum, colsum, bpart, (float*)d_out);
}

// Round 3
// 91.376 us; speedup vs baseline: 2.3469x; 1.3248x over previous
//
#include <hip/hip_runtime.h>

// VDR (Student-t kernel MMD variance) — fused one-pass.
// sum((K - rm - cm + t)^2) == sum(K^2) - sum(rowsum^2)/n - sum(colsum^2)/m + T^2/(mn)
// Gram via f16 MFMA. Diagonal of K_XX/K_YY forced to GAMMA (exact in ref).
// R1: removed S2 hot-line atomic (191->93us).
// R2: remove ALL atomics. rowsum/colsum go to per-block partial slabs via
// plain coalesced stores (device atomics on 8-XCD execute at the coherence
// point -> 15.4MB write-through + per-line serialization was the 93us).
// Parallel 2-stage reduction replaces the serial single-block final.

typedef __attribute__((ext_vector_type(8))) _Float16 f16x8;
typedef __attribute__((ext_vector_type(2))) _Float16 f16x2;
typedef __attribute__((ext_vector_type(4))) float f32x4;

#define N4096 4096
#define GAMMA_F 0.50241665f   // gamma(0.8)/(gamma(0.3)*sqrt(0.6))

// workspace layout (bytes)
#define OFF_SQ1     0         // float sq1[4096]
#define OFF_SQ2     16384     // float sq2[4096]
#define OFF_H1      32768     // _Float16 H1[4096*128]   (1 MB)
#define OFF_H2      1081344   // _Float16 H2[4096*128]   (1 MB)
#define OFF_RSP     2129920   // float rowsum_part[3][32][4096]  (1.5 MB)
#define OFF_CSP     3702784   // float colsum_part[3][32][4096]  (1.5 MB)
#define OFF_BPART   5275648   // float bpart[3][1024]
#define OFF_PARTA   5287936   // double partA[3][16][4]  {sr,sc,t,s2}

// ---- prep: fp32 -> f16 convert + squared row norms (one wave per row) ----
__global__ __launch_bounds__(256) void vdr_prep(const float* __restrict__ X1,
                                                const float* __restrict__ X2,
                                                _Float16* __restrict__ H1,
                                                _Float16* __restrict__ H2,
                                                float* __restrict__ sq1,
                                                float* __restrict__ sq2) {
  const int gw = (blockIdx.x * 256 + threadIdx.x) >> 6;  // global wave = row over [0, 8192)
  const int lane = threadIdx.x & 63;
  const float* X; _Float16* H; float* SQ; int row;
  if (gw < N4096) { X = X1; H = H1; SQ = sq1; row = gw; }
  else            { X = X2; H = H2; SQ = sq2; row = gw - N4096; }
  const float2 v = reinterpret_cast<const float2*>(X + (size_t)row * 128)[lane];
  f16x2 h; h.x = (_Float16)v.x; h.y = (_Float16)v.y;
  reinterpret_cast<f16x2*>(H + (size_t)row * 128)[lane] = h;
  float s = v.x * v.x + v.y * v.y;
  #pragma unroll
  for (int o = 32; o; o >>= 1) s += __shfl_xor(s, o);
  if (lane == 0) SQ[row] = s;
}

// ---- main: per 128x128 tile of one of {XX, XY, YY}: MFMA gram -> K -> sums ----
__global__ __launch_bounds__(256) void vdr_main(const _Float16* __restrict__ H1,
                                                const _Float16* __restrict__ H2,
                                                const float* __restrict__ sq1,
                                                const float* __restrict__ sq2,
                                                float* __restrict__ rsp,
                                                float* __restrict__ csp,
                                                float* __restrict__ bpart) {
  const int z = blockIdx.z;                       // 0:XX 1:XY 2:YY
  const _Float16* Ap = (z == 2) ? H2 : H1;
  const _Float16* Bp = (z == 0) ? H1 : H2;
  const float* asq = (z == 2) ? sq2 : sq1;
  const float* bsq = (z == 0) ? sq1 : sq2;
  const bool diag = (z != 1);

  const int w = threadIdx.x >> 6;
  const int lane = threadIdx.x & 63;
  const int lr = lane & 15, lg = lane >> 4;
  const int row0 = blockIdx.x * 128 + (w >> 1) * 64;   // wave's 64x64 sub-tile
  const int col0 = blockIdx.y * 128 + (w & 1) * 64;

  f32x4 acc[4][4];
  #pragma unroll
  for (int mi = 0; mi < 4; ++mi)
    #pragma unroll
    for (int ni = 0; ni < 4; ++ni)
      acc[mi][ni] = (f32x4){0.f, 0.f, 0.f, 0.f};

  // A frag (16x16x32 f16): row = lane%16, k = 8*(lane/16)+e ; B mirrors with col = lane%16.
  #pragma unroll
  for (int ks = 0; ks < 4; ++ks) {
    const int ko = ks * 32 + lg * 8;
    f16x8 a[4], b[4];
    #pragma unroll
    for (int mi = 0; mi < 4; ++mi)
      a[mi] = *reinterpret_cast<const f16x8*>(Ap + (size_t)(row0 + mi * 16 + lr) * 128 + ko);
    #pragma unroll
    for (int ni = 0; ni < 4; ++ni)
      b[ni] = *reinterpret_cast<const f16x8*>(Bp + (size_t)(col0 + ni * 16 + lr) * 128 + ko);
    #pragma unroll
    for (int mi = 0; mi < 4; ++mi)
      #pragma unroll
      for (int ni = 0; ni < 4; ++ni)
        acc[mi][ni] = __builtin_amdgcn_mfma_f32_16x16x32_f16(a[mi], b[ni], acc[mi][ni], 0, 0, 0);
  }

  float bsqc[4];
  #pragma unroll
  for (int ni = 0; ni < 4; ++ni) bsqc[ni] = bsq[col0 + ni * 16 + lr];

  float k2s = 0.f;
  float cpart[4] = {0.f, 0.f, 0.f, 0.f};

  __shared__ float rs_buf[2][128];
  __shared__ float cs_buf[2][128];
  __shared__ float sred[4];

  // C/D layout: col = lane&15, row = (lane>>4)*4 + reg   [m89/m91 verified]
  #pragma unroll
  for (int mi = 0; mi < 4; ++mi) {
    #pragma unroll
    for (int reg = 0; reg < 4; ++reg) {
      const int grow = row0 + mi * 16 + lg * 4 + reg;
      const float asr = asq[grow];
      float rp = 0.f;
      #pragma unroll
      for (int ni = 0; ni < 4; ++ni) {
        const int gcol = col0 + ni * 16 + lr;
        const float G = acc[mi][ni][reg];
        float Kv;
        if (diag && grow == gcol) {
          Kv = GAMMA_F;                                   // d2 == 0 exactly in ref
        } else {
          const float base = 1.0f + 0.5f * (asr + bsqc[ni] - 2.0f * G);
          Kv = GAMMA_F * __builtin_amdgcn_exp2f(-0.8f * __builtin_amdgcn_logf(base));
        }
        rp += Kv;
        cpart[ni] += Kv;
        k2s += Kv * Kv;
      }
      // rows live on lanes sharing lg: reduce across the 16-lane (lr) group
      #pragma unroll
      for (int o = 1; o < 16; o <<= 1) rp += __shfl_xor(rp, o);
      if (lr == 0)
        rs_buf[w & 1][(w >> 1) * 64 + mi * 16 + lg * 4 + reg] = rp;
    }
  }
  #pragma unroll
  for (int ni = 0; ni < 4; ++ni) {
    float cp = cpart[ni];
    cp += __shfl_xor(cp, 16);
    cp += __shfl_xor(cp, 32);
    if (lg == 0)
      cs_buf[w >> 1][(w & 1) * 64 + ni * 16 + lr] = cp;
  }
  #pragma unroll
  for (int o = 32; o; o >>= 1) k2s += __shfl_xor(k2s, o);
  if (lane == 0) sred[w] = k2s;
  __syncthreads();

  const int tid = threadIdx.x;
  if (tid < 128) {
    rsp[(size_t)(z * 32 + blockIdx.y) * 4096 + blockIdx.x * 128 + tid] =
        rs_buf[0][tid] + rs_buf[1][tid];
  } else {
    const int t = tid - 128;
    csp[(size_t)(z * 32 + blockIdx.x) * 4096 + blockIdx.y * 128 + t] =
        cs_buf[0][t] + cs_buf[1][t];
  }
  if (tid == 0)
    bpart[z * 1024 + blockIdx.y * 32 + blockIdx.x] =
        sred[0] + sred[1] + sred[2] + sred[3];
}

// ---- stage A: per (chunk, matrix) partial reduce in f64 ----
__global__ __launch_bounds__(256) void vdr_reduceA(const float* __restrict__ rsp,
                                                   const float* __restrict__ csp,
                                                   const float* __restrict__ bpart,
                                                   double* __restrict__ partA) {
  const int i = blockIdx.x, m = blockIdx.y, tid = threadIdx.x;
  const float* rbase = rsp + (size_t)m * 32 * 4096 + i * 256 + tid;
  const float* cbase = csp + (size_t)m * 32 * 4096 + i * 256 + tid;
  double rs = 0.0, cs = 0.0;
  #pragma unroll
  for (int by = 0; by < 32; ++by) {
    rs += (double)rbase[(size_t)by * 4096];
    cs += (double)cbase[(size_t)by * 4096];
  }
  double sr = rs * rs, sc = cs * cs, t = rs;
  double s2 = (tid < 64) ? (double)bpart[m * 1024 + i * 64 + tid] : 0.0;
  #pragma unroll
  for (int o = 32; o; o >>= 1) {
    sr += __shfl_down(sr, o);
    sc += __shfl_down(sc, o);
    t  += __shfl_down(t, o);
    s2 += __shfl_down(s2, o);
  }
  __shared__ double sh[4][4];
  const int lane = tid & 63, wid = tid >> 6;
  if (lane == 0) { sh[wid][0] = sr; sh[wid][1] = sc; sh[wid][2] = t; sh[wid][3] = s2; }
  __syncthreads();
  if (tid < 4)
    partA[(size_t)(m * 16 + i) * 4 + tid] =
        sh[0][tid] + sh[1][tid] + sh[2][tid] + sh[3][tid];
}

// ---- stage B: combine 48 partials, apply unbiased formula ----
__global__ void vdr_reduceB(const double* __restrict__ partA,
                            float* __restrict__ out) {
  const int tid = threadIdx.x;
  double sr = 0.0, sc = 0.0, t = 0.0, s2 = 0.0;
  if (tid < 48) {
    const double* p = partA + (size_t)tid * 4;
    sr = p[0]; sc = p[1]; t = p[2]; s2 = p[3];
  }
  #pragma unroll
  for (int o = 8; o; o >>= 1) {
    sr += __shfl_down(sr, o, 16);
    sc += __shfl_down(sc, o, 16);
    t  += __shfl_down(t, o, 16);
    s2 += __shfl_down(s2, o, 16);
  }
  __shared__ double res[3];
  if (tid < 48 && (tid & 15) == 0) {
    const double inv = 1.0 / 4096.0;
    res[tid >> 4] = s2 - sr * inv - sc * inv + t * t * inv * inv;
  }
  __syncthreads();
  if (tid == 0) {
    const double mf = 4096.0;
    out[0] = (float)((res[0] - mf) / ((mf - 1.0) * mf)
                   + (res[2] - mf) / ((mf - 1.0) * mf)
                   - 2.0 * res[1] / (mf * mf));
  }
}

extern "C" void kernel_launch(void* const* d_in, const int* in_sizes, int n_in,
                              void* d_out, int out_size, void* d_ws, size_t ws_size,
                              hipStream_t stream) {
  const float* X1 = (const float*)d_in[0];
  const float* X2 = (const float*)d_in[1];
  char* ws = (char*)d_ws;
  float* sq1      = (float*)(ws + OFF_SQ1);
  float* sq2      = (float*)(ws + OFF_SQ2);
  _Float16* H1    = (_Float16*)(ws + OFF_H1);
  _Float16* H2    = (_Float16*)(ws + OFF_H2);
  float* rsp      = (float*)(ws + OFF_RSP);
  float* csp      = (float*)(ws + OFF_CSP);
  float* bpart    = (float*)(ws + OFF_BPART);
  double* partA   = (double*)(ws + OFF_PARTA);

  vdr_prep<<<2048, 256, 0, stream>>>(X1, X2, H1, H2, sq1, sq2);
  dim3 grid(32, 32, 3);
  vdr_main<<<grid, 256, 0, stream>>>(H1, H2, sq1, sq2, rsp, csp, bpart);
  dim3 ga(16, 3);
  vdr_reduceA<<<ga, 256, 0, stream>>>(rsp, csp, bpart, partA);
  vdr_reduceB<<<1, 64, 0, stream>>>(partA, (float*)d_out);
}

// Round 4
// 64.503 us; speedup vs baseline: 3.3246x; 1.4166x over previous
//
#include <hip/hip_runtime.h>

// VDR (Student-t kernel MMD variance) — fused one-pass, no K materialization.
// sum((K-rm-cm+t)^2) == sum(K^2) - sum(rowsum^2)/n - sum(colsum^2)/m + T^2/(mn)
// R1: removed S2 hot-line atomic (191->93us). R2: removed all atomics (->83us).
// R3: (a) epilogue reduces restructured — the 64 chained ds_bpermute row-reduces
// per wave (~6-7k serial cycles) replaced by LDS transpose-buffer writes + one
// b128 read pass; (b) XX/YY computed upper-triangular only (symmetry, 1.48x
// work cut); (c) asq as float4 loads, per-col constants hoisted.

typedef __attribute__((ext_vector_type(8))) _Float16 f16x8;
typedef __attribute__((ext_vector_type(2))) _Float16 f16x2;
typedef __attribute__((ext_vector_type(4))) float f32x4;

#define N4096 4096
#define GAMMA_F 0.50241665f   // gamma(0.8)/(gamma(0.3)*sqrt(0.6))
#define SLABSZ (32 * 4096)

// workspace layout (bytes)
#define OFF_SQ1     0         // float sq1[4096]
#define OFF_SQ2     16384     // float sq2[4096]
#define OFF_H1      32768     // _Float16 H1[4096*128]   (1 MB)
#define OFF_H2      1081344   // _Float16 H2[4096*128]   (1 MB)
#define OFF_SLABS   2129920   // float slabs[4][32][4096] : rsXX, rsXY, csXY, rsYY (2 MB)
#define OFF_BPART   4227072   // float bpart[2080]
#define OFF_PARTA   4235392   // double partA[4][16][2] {sum_sq, sum}

// ---- prep: fp32 -> f16 convert + squared row norms (one wave per row) ----
__global__ __launch_bounds__(256) void vdr_prep(const float* __restrict__ X1,
                                                const float* __restrict__ X2,
                                                _Float16* __restrict__ H1,
                                                _Float16* __restrict__ H2,
                                                float* __restrict__ sq1,
                                                float* __restrict__ sq2) {
  const int gw = (blockIdx.x * 256 + threadIdx.x) >> 6;
  const int lane = threadIdx.x & 63;
  const float* X; _Float16* H; float* SQ; int row;
  if (gw < N4096) { X = X1; H = H1; SQ = sq1; row = gw; }
  else            { X = X2; H = H2; SQ = sq2; row = gw - N4096; }
  const float2 v = reinterpret_cast<const float2*>(X + (size_t)row * 128)[lane];
  f16x2 h; h.x = (_Float16)v.x; h.y = (_Float16)v.y;
  reinterpret_cast<f16x2*>(H + (size_t)row * 128)[lane] = h;
  float s = v.x * v.x + v.y * v.y;
  #pragma unroll
  for (int o = 32; o; o >>= 1) s += __shfl_xor(s, o);
  if (lane == 0) SQ[row] = s;
}

// per-thread epilogue: K from Gram, accumulate row partials into LDS transpose
// buffer (no chained cross-lane reduce), col partials + K^2 in registers.
template<bool DIAGCHK>
__device__ __forceinline__ void epilogue_t(const f32x4 (*acc)[4],
                                           const float* __restrict__ asq,
                                           const float* cb,
                                           int row0, int col0, int lr, int lg,
                                           float (*rs_area)[16],
                                           float* cpart, float& k2s) {
  #pragma unroll
  for (int mi = 0; mi < 4; ++mi) {
    const float4 aq = *reinterpret_cast<const float4*>(asq + row0 + mi * 16 + lg * 4);
    const float aqv[4] = {aq.x, aq.y, aq.z, aq.w};
    #pragma unroll
    for (int rg = 0; rg < 4; ++rg) {
      const float pre = __builtin_fmaf(0.5f, aqv[rg], 1.0f);
      float rp = 0.f;
      #pragma unroll
      for (int ni = 0; ni < 4; ++ni) {
        const float G = acc[mi][ni][rg];
        const float base = (pre + cb[ni]) - G;
        float Kv = GAMMA_F * __builtin_amdgcn_exp2f(-0.8f * __builtin_amdgcn_logf(base));
        if (DIAGCHK) {
          if ((row0 + mi * 16 + lg * 4 + rg) == (col0 + ni * 16 + lr)) Kv = GAMMA_F;
        }
        rp += Kv;
        cpart[ni] += Kv;
        k2s = __builtin_fmaf(Kv, Kv, k2s);
      }
      rs_area[mi * 16 + lg * 4 + rg][lr] = rp;   // pipelined ds_write, no chain
    }
  }
}

// ---- main: one 128x128 tile per block. Tiles: XX upper-tri (528), XY full
// (1024), YY upper-tri (528). grid = 2080 x 256 threads. ----
__global__ __launch_bounds__(256) void vdr_main(const _Float16* __restrict__ H1,
                                                const _Float16* __restrict__ H2,
                                                const float* __restrict__ sq1,
                                                const float* __restrict__ sq2,
                                                float* __restrict__ slabs,
                                                float* __restrict__ bpart) {
  // ---- decode tile ----
  int t = blockIdx.x, z, bi, bj;
  if (t < 528) z = 0;
  else if (t < 1552) { z = 1; t -= 528; }
  else { z = 2; t -= 1552; }
  if (z == 1) { bi = t >> 5; bj = t & 31; }
  else {
    bi = (int)((65.0 - sqrt(4225.0 - 8.0 * (double)t)) * 0.5);
    while (bi > 0 && bi * 32 - bi * (bi - 1) / 2 > t) --bi;
    while ((bi + 1) * 32 - (bi + 1) * bi / 2 <= t) ++bi;
    bj = bi + (t - (bi * 32 - bi * (bi - 1) / 2));
  }
  const _Float16* Ap = (z == 2) ? H2 : H1;
  const _Float16* Bp = (z == 0) ? H1 : H2;
  const float* asq = (z == 2) ? sq2 : sq1;
  const float* bsq = (z == 0) ? sq1 : sq2;
  const bool hasdiag = (z != 1) && (bi == bj);

  const int w = threadIdx.x >> 6;
  const int lane = threadIdx.x & 63;
  const int lr = lane & 15, lg = lane >> 4;
  const int row0 = bi * 128 + (w >> 1) * 64;
  const int col0 = bj * 128 + (w & 1) * 64;

  f32x4 acc[4][4];
  #pragma unroll
  for (int mi = 0; mi < 4; ++mi)
    #pragma unroll
    for (int ni = 0; ni < 4; ++ni)
      acc[mi][ni] = (f32x4){0.f, 0.f, 0.f, 0.f};

  // A frag (16x16x32 f16): row = lane%16, k = 8*(lane/16)+e ; B mirrors.
  #pragma unroll
  for (int ks = 0; ks < 4; ++ks) {
    const int ko = ks * 32 + lg * 8;
    f16x8 a[4], b[4];
    #pragma unroll
    for (int mi = 0; mi < 4; ++mi)
      a[mi] = *reinterpret_cast<const f16x8*>(Ap + (size_t)(row0 + mi * 16 + lr) * 128 + ko);
    #pragma unroll
    for (int ni = 0; ni < 4; ++ni)
      b[ni] = *reinterpret_cast<const f16x8*>(Bp + (size_t)(col0 + ni * 16 + lr) * 128 + ko);
    #pragma unroll
    for (int mi = 0; mi < 4; ++mi)
      #pragma unroll
      for (int ni = 0; ni < 4; ++ni)
        acc[mi][ni] = __builtin_amdgcn_mfma_f32_16x16x32_f16(a[mi], b[ni], acc[mi][ni], 0, 0, 0);
  }

  float cb[4];
  #pragma unroll
  for (int ni = 0; ni < 4; ++ni) cb[ni] = 0.5f * bsq[col0 + ni * 16 + lr];

  __shared__ float rs_lds[4][64][16];   // per-wave transpose area
  __shared__ float rs_sum[4][64];
  __shared__ float cs_sum[4][64];
  __shared__ float sred[4];

  float cpart[4] = {0.f, 0.f, 0.f, 0.f};
  float k2s = 0.f;

  if (hasdiag)
    epilogue_t<true >(acc, asq, cb, row0, col0, lr, lg, rs_lds[w], cpart, k2s);
  else
    epilogue_t<false>(acc, asq, cb, row0, col0, lr, lg, rs_lds[w], cpart, k2s);

  __syncthreads();   // transpose-area writes visible (incl. cross-lane)

  // per-wave: sum the 16 partials of own row (pipelined b128 reads)
  float rsum = 0.f;
  #pragma unroll
  for (int j = 0; j < 4; ++j) {
    const f32x4 v = *reinterpret_cast<const f32x4*>(&rs_lds[w][lane][j * 4]);
    rsum += (v[0] + v[1]) + (v[2] + v[3]);
  }
  rs_sum[w][lane] = rsum;

  #pragma unroll
  for (int ni = 0; ni < 4; ++ni) {
    float cp = cpart[ni];
    cp += __shfl_xor(cp, 16);
    cp += __shfl_xor(cp, 32);
    if (lane < 16) cs_sum[w][ni * 16 + lane] = cp;
  }
  #pragma unroll
  for (int o = 32; o; o >>= 1) k2s += __shfl_xor(k2s, o);
  if (lane == 0) sred[w] = k2s;
  __syncthreads();

  // ---- block combine + global stores (plain coalesced, unique writers) ----
  float* rowslab = slabs + (size_t)((z == 0) ? 0 : (z == 1) ? 1 : 3) * SLABSZ;
  float* colslab = slabs + (size_t)((z == 0) ? 0 : (z == 1) ? 2 : 3) * SLABSZ;
  const int tid = threadIdx.x;
  if (tid < 128) {
    const int r = tid;   // waves 2h, 2h+1 cover row-half h
    const float v = rs_sum[(r >> 6) * 2][r & 63] + rs_sum[(r >> 6) * 2 + 1][r & 63];
    rowslab[(size_t)bj * 4096 + bi * 128 + r] = v;
  } else {
    const int c = tid - 128;   // waves h, h+2 cover col-half h
    const float v = cs_sum[c >> 6][c & 63] + cs_sum[(c >> 6) + 2][c & 63];
    if (!(z != 1 && bi == bj))   // diag tri-block: col partial == row partial, skip
      colslab[(size_t)bi * 4096 + bj * 128 + c] = v;
  }
  if (tid == 0) {
    const float wtf = (z != 1 && bi != bj) ? 2.f : 1.f;   // mirrored tile
    bpart[blockIdx.x] = (sred[0] + sred[1] + sred[2] + sred[3]) * wtf;
  }
}

// ---- stage A: per (chunk, slab) reduce: sum 32 partial slabs, emit {sum^2, sum} ----
__global__ __launch_bounds__(256) void vdr_reduceA(const float* __restrict__ slabs,
                                                   double* __restrict__ partA) {
  const int j = blockIdx.y, tid = threadIdx.x;
  const int e = blockIdx.x * 256 + tid;
  const float* base = slabs + (size_t)j * SLABSZ + e;
  double s = 0.0;
  #pragma unroll
  for (int k = 0; k < 32; ++k) s += (double)base[(size_t)k * 4096];
  double sq = s * s, sm = s;
  #pragma unroll
  for (int o = 32; o; o >>= 1) { sq += __shfl_down(sq, o); sm += __shfl_down(sm, o); }
  __shared__ double sh[4][2];
  const int lane = tid & 63, wid = tid >> 6;
  if (lane == 0) { sh[wid][0] = sq; sh[wid][1] = sm; }
  __syncthreads();
  if (tid == 0) {
    partA[(size_t)(j * 16 + blockIdx.x) * 2 + 0] = sh[0][0] + sh[1][0] + sh[2][0] + sh[3][0];
    partA[(size_t)(j * 16 + blockIdx.x) * 2 + 1] = sh[0][1] + sh[1][1] + sh[2][1] + sh[3][1];
  }
}

// ---- stage B: combine partials + bpart, apply unbiased formula ----
__global__ __launch_bounds__(256) void vdr_reduceB(const double* __restrict__ partA,
                                                   const float* __restrict__ bpart,
                                                   float* __restrict__ out) {
  const int tid = threadIdx.x;
  __shared__ double ssq[4], ssum[4], s2sh[4][3];
  double s2[3] = {0.0, 0.0, 0.0};
  for (int i = tid; i < 2080; i += 256) {
    const double v = (double)bpart[i];
    if (i < 528) s2[0] += v; else if (i < 1552) s2[1] += v; else s2[2] += v;
  }
  #pragma unroll
  for (int o = 32; o; o >>= 1) {
    s2[0] += __shfl_down(s2[0], o);
    s2[1] += __shfl_down(s2[1], o);
    s2[2] += __shfl_down(s2[2], o);
  }
  const int lane = tid & 63, wid = tid >> 6;
  if (lane == 0) { s2sh[wid][0] = s2[0]; s2sh[wid][1] = s2[1]; s2sh[wid][2] = s2[2]; }
  if (tid < 64) {
    const int j = tid >> 4, c = tid & 15;
    double sq = partA[(size_t)(j * 16 + c) * 2 + 0];
    double sm = partA[(size_t)(j * 16 + c) * 2 + 1];
    #pragma unroll
    for (int o = 8; o; o >>= 1) { sq += __shfl_down(sq, o, 16); sm += __shfl_down(sm, o, 16); }
    if (c == 0) { ssq[j] = sq; ssum[j] = sm; }
  }
  __syncthreads();
  if (tid == 0) {
    const double S2XX = s2sh[0][0] + s2sh[1][0] + s2sh[2][0] + s2sh[3][0];
    const double S2XY = s2sh[0][1] + s2sh[1][1] + s2sh[2][1] + s2sh[3][1];
    const double S2YY = s2sh[0][2] + s2sh[1][2] + s2sh[2][2] + s2sh[3][2];
    const double inv = 1.0 / 4096.0;
    const double r0 = S2XX - 2.0 * ssq[0] * inv + ssum[0] * ssum[0] * inv * inv;
    const double r1 = S2XY - ssq[1] * inv - ssq[2] * inv + ssum[1] * ssum[1] * inv * inv;
    const double r2 = S2YY - 2.0 * ssq[3] * inv + ssum[3] * ssum[3] * inv * inv;
    const double mf = 4096.0;
    out[0] = (float)((r0 - mf) / ((mf - 1.0) * mf)
                   + (r2 - mf) / ((mf - 1.0) * mf)
                   - 2.0 * r1 / (mf * mf));
  }
}

extern "C" void kernel_launch(void* const* d_in, const int* in_sizes, int n_in,
                              void* d_out, int out_size, void* d_ws, size_t ws_size,
                              hipStream_t stream) {
  const float* X1 = (const float*)d_in[0];
  const float* X2 = (const float*)d_in[1];
  char* ws = (char*)d_ws;
  float* sq1      = (float*)(ws + OFF_SQ1);
  float* sq2      = (float*)(ws + OFF_SQ2);
  _Float16* H1    = (_Float16*)(ws + OFF_H1);
  _Float16* H2    = (_Float16*)(ws + OFF_H2);
  float* slabs    = (float*)(ws + OFF_SLABS);
  float* bpart    = (float*)(ws + OFF_BPART);
  double* partA   = (double*)(ws + OFF_PARTA);

  vdr_prep<<<2048, 256, 0, stream>>>(X1, X2, H1, H2, sq1, sq2);
  vdr_main<<<2080, 256, 0, stream>>>(H1, H2, sq1, sq2, slabs, bpart);
  dim3 ga(16, 4);
  vdr_reduceA<<<ga, 256, 0, stream>>>(slabs, partA);
  vdr_reduceB<<<1, 256, 0, stream>>>(partA, bpart, (float*)d_out);
}

// Round 5
// 57.697 us; speedup vs baseline: 3.7168x; 1.1180x over previous
//
#include <hip/hip_runtime.h>

// VDR (Student-t kernel MMD variance) — fused, no K materialization.
// sum((K-rm-cm+t)^2) == sum(K^2) - sum(rowsum^2)/n - sum(colsum^2)/m + T^2/(mn)
// R1: killed S2 hot-line atomic. R2: killed all atomics. R3: tri symmetry.
// R4 finding: per-block time invariant ~6.5us across all epilogue variants ->
// latency-bound with no effective overlap. R5: independent 64x64-tile WAVE
// workers looping over ~4 tiles with cross-tile pipelining (next tile's
// fragment loads issued before the trans-heavy epilogue; sched_barrier(0)
// pins them). No barriers; wave-private LDS; per-wave k2s accumulators.

typedef __attribute__((ext_vector_type(8))) _Float16 f16x8;
typedef __attribute__((ext_vector_type(2))) _Float16 f16x2;
typedef __attribute__((ext_vector_type(4))) float f32x4;

#define GAMMA_F 0.50241665f   // gamma(0.8)/(gamma(0.3)*sqrt(0.6))
#define NTILES 8256           // 2080 XX-tri + 4096 XY + 2080 YY (64x64 tiles)
#define NWAVES 2048
#define SLAB (64 * 4096)

// workspace layout (bytes)
#define OFF_SQ1   0                       // float sq1[4096]
#define OFF_SQ2   16384                   // float sq2[4096]
#define OFF_H1    32768                   // _Float16 H1[4096*128]
#define OFF_H2    1081344                 // _Float16 H2[4096*128]
#define OFF_SLABS 2129920                 // float slabs[4][64][4096] {XX, XYr, XYc, YY}
#define OFF_BPART (2129920 + 4194304)     // float bpart[3][2048]
#define OFF_PARTA (OFF_BPART + 24576)     // double partA[4][16][2]

// ---- prep: fp32 -> f16 convert + squared row norms (one wave per row) ----
__global__ __launch_bounds__(256) void vdr_prep(const float* __restrict__ X1,
                                                const float* __restrict__ X2,
                                                _Float16* __restrict__ H1,
                                                _Float16* __restrict__ H2,
                                                float* __restrict__ sq1,
                                                float* __restrict__ sq2) {
  const int gw = (blockIdx.x * 256 + threadIdx.x) >> 6;
  const int lane = threadIdx.x & 63;
  const float* X; _Float16* H; float* SQ; int row;
  if (gw < 4096) { X = X1; H = H1; SQ = sq1; row = gw; }
  else           { X = X2; H = H2; SQ = sq2; row = gw - 4096; }
  const float2 v = reinterpret_cast<const float2*>(X + (size_t)row * 128)[lane];
  f16x2 h; h.x = (_Float16)v.x; h.y = (_Float16)v.y;
  reinterpret_cast<f16x2*>(H + (size_t)row * 128)[lane] = h;
  float s = v.x * v.x + v.y * v.y;
  #pragma unroll
  for (int o = 32; o; o >>= 1) s += __shfl_xor(s, o);
  if (lane == 0) SQ[row] = s;
}

// upper-triangle 64x64-tile decode: u in [0,2080) -> (bi, bj), bi<=bj
__device__ __forceinline__ void tri_decode(int u, int& bi, int& bj) {
  int b = (int)(64.5f - sqrtf(4160.25f - 2.0f * (float)u));
  if (b < 0) b = 0; if (b > 63) b = 63;
  while (b > 0 && (b * (129 - b)) / 2 > u) --b;
  while (b < 63 && ((b + 1) * (128 - b)) / 2 <= u) ++b;
  bi = b;
  bj = b + (u - (b * (129 - b)) / 2);
}

// ---- main: 2048 independent wave workers, ~4 pipelined 64x64 tiles each ----
__global__ __launch_bounds__(256) void vdr_main(const _Float16* __restrict__ H1,
                                                const _Float16* __restrict__ H2,
                                                const float* __restrict__ sq1,
                                                const float* __restrict__ sq2,
                                                float* __restrict__ slabs,
                                                float* __restrict__ bpart) {
  const int w = threadIdx.x >> 6, lane = threadIdx.x & 63;
  const int lr = lane & 15, lg = lane >> 4;
  const int gw = blockIdx.x * 4 + w;

  __shared__ float rs_area_s[4][16][65];   // wave-private transpose area
  __shared__ float colbuf_s[4][64];        // wave-private col gather
  float (*rs_area)[65] = rs_area_s[w];
  float* colbuf = colbuf_s[w];

  float kxx = 0.f, kxy = 0.f, kyy = 0.f;

  int z, bi, bj; const _Float16 *A, *B; const float *as, *bs;
  auto decode = [&](int T, int& z_, int& bi_, int& bj_, const _Float16*& A_,
                    const _Float16*& B_, const float*& as_, const float*& bs_) {
    if (T < 2080)      { z_ = 0; tri_decode(T, bi_, bj_);          A_ = H1; B_ = H1; as_ = sq1; bs_ = sq1; }
    else if (T < 6176) { z_ = 1; int v = T - 2080; bi_ = v >> 6; bj_ = v & 63;
                                                                   A_ = H1; B_ = H2; as_ = sq1; bs_ = sq2; }
    else               { z_ = 2; tri_decode(T - 6176, bi_, bj_);   A_ = H2; B_ = H2; as_ = sq2; bs_ = sq2; }
  };

  int t = gw;
  decode(t, z, bi, bj, A, B, as, bs);

  f16x8 pa[4], pb[4];                       // ks=0 fragments (prefetched)
  {
    const int ko = lg * 8;
    #pragma unroll
    for (int mi = 0; mi < 4; ++mi)
      pa[mi] = *reinterpret_cast<const f16x8*>(A + (size_t)(bi * 64 + mi * 16 + lr) * 128 + ko);
    #pragma unroll
    for (int ni = 0; ni < 4; ++ni)
      pb[ni] = *reinterpret_cast<const f16x8*>(B + (size_t)(bj * 64 + ni * 16 + lr) * 128 + ko);
  }

  while (t < NTILES) {
    f32x4 acc[4][4];
    #pragma unroll
    for (int mi = 0; mi < 4; ++mi)
      #pragma unroll
      for (int ni = 0; ni < 4; ++ni)
        acc[mi][ni] = (f32x4){0.f, 0.f, 0.f, 0.f};

    // ks = 0 from prefetched fragments
    #pragma unroll
    for (int mi = 0; mi < 4; ++mi)
      #pragma unroll
      for (int ni = 0; ni < 4; ++ni)
        acc[mi][ni] = __builtin_amdgcn_mfma_f32_16x16x32_f16(pa[mi], pb[ni], acc[mi][ni], 0, 0, 0);

    // ks = 1..3
    #pragma unroll
    for (int ks = 1; ks < 4; ++ks) {
      const int ko = ks * 32 + lg * 8;
      f16x8 a[4], b[4];
      #pragma unroll
      for (int mi = 0; mi < 4; ++mi)
        a[mi] = *reinterpret_cast<const f16x8*>(A + (size_t)(bi * 64 + mi * 16 + lr) * 128 + ko);
      #pragma unroll
      for (int ni = 0; ni < 4; ++ni)
        b[ni] = *reinterpret_cast<const f16x8*>(B + (size_t)(bj * 64 + ni * 16 + lr) * 128 + ko);
      #pragma unroll
      for (int mi = 0; mi < 4; ++mi)
        #pragma unroll
        for (int ni = 0; ni < 4; ++ni)
          acc[mi][ni] = __builtin_amdgcn_mfma_f32_16x16x32_f16(a[mi], b[ni], acc[mi][ni], 0, 0, 0);
    }

    // ---- prefetch next tile's ks=0 fragments (latency hides under epilogue) ----
    const int tn = t + NWAVES;
    const bool more = tn < NTILES;
    int zn, bin, bjn; const _Float16 *An = A, *Bn = B; const float *asn = as, *bsn = bs;
    if (more) {
      decode(tn, zn, bin, bjn, An, Bn, asn, bsn);
      const int ko = lg * 8;
      #pragma unroll
      for (int mi = 0; mi < 4; ++mi)
        pa[mi] = *reinterpret_cast<const f16x8*>(An + (size_t)(bin * 64 + mi * 16 + lr) * 128 + ko);
      #pragma unroll
      for (int ni = 0; ni < 4; ++ni)
        pb[ni] = *reinterpret_cast<const f16x8*>(Bn + (size_t)(bjn * 64 + ni * 16 + lr) * 128 + ko);
    }
    __builtin_amdgcn_sched_barrier(0);   // pin prefetch issue before epilogue

    // ---- epilogue for tile t ----
    float cb[4];
    #pragma unroll
    for (int ni = 0; ni < 4; ++ni) cb[ni] = 0.5f * bs[bj * 64 + ni * 16 + lr];
    const bool dg = (z != 1) && (bi == bj);
    float tk = 0.f;
    float cpart[4] = {0.f, 0.f, 0.f, 0.f};

    #pragma unroll
    for (int mi = 0; mi < 4; ++mi) {
      const float4 aq = *reinterpret_cast<const float4*>(as + bi * 64 + mi * 16 + lg * 4);
      const float aqv[4] = {aq.x, aq.y, aq.z, aq.w};
      #pragma unroll
      for (int rg = 0; rg < 4; ++rg) {
        const float pre = __builtin_fmaf(0.5f, aqv[rg], 1.0f);
        float rp = 0.f;
        #pragma unroll
        for (int ni = 0; ni < 4; ++ni) {
          const float G = acc[mi][ni][rg];
          const float base = (pre + cb[ni]) - G;
          float Kv = GAMMA_F * __builtin_amdgcn_exp2f(-0.8f * __builtin_amdgcn_logf(base));
          if (dg) { if ((mi * 16 + lg * 4 + rg) == (ni * 16 + lr)) Kv = GAMMA_F; }
          rp += Kv;
          cpart[ni] += Kv;
          tk = __builtin_fmaf(Kv, Kv, tk);
        }
        rs_area[lr][mi * 16 + lg * 4 + rg] = rp;   // [16][65]: 2-way conflict = free
      }
    }
    const float wt = (z != 1 && bi != bj) ? 2.f : 1.f;
    if (z == 0) kxx = __builtin_fmaf(wt, tk, kxx);
    else if (z == 1) kxy += tk;
    else kyy = __builtin_fmaf(wt, tk, kyy);

    float rsum = 0.f;
    #pragma unroll
    for (int j = 0; j < 16; ++j) rsum += rs_area[j][lane];   // conflict-free reads

    #pragma unroll
    for (int ni = 0; ni < 4; ++ni) {
      float cp = cpart[ni];
      cp += __shfl_xor(cp, 16);
      cp += __shfl_xor(cp, 32);
      if (lg == 0) colbuf[ni * 16 + lr] = cp;
    }
    const float cval = colbuf[lane];

    float* rowslab = slabs + (size_t)((z == 0) ? 0 : (z == 1) ? 1 : 3) * SLAB;
    rowslab[(size_t)bj * 4096 + bi * 64 + lane] = rsum;
    if (z == 1)
      slabs[(size_t)2 * SLAB + (size_t)bi * 4096 + bj * 64 + lane] = cval;
    else if (bi != bj)
      rowslab[(size_t)bi * 4096 + bj * 64 + lane] = cval;   // mirror (symmetry)

    if (more) { z = zn; bi = bin; bj = bjn; A = An; B = Bn; as = asn; bs = bsn; }
    t = tn;
  }

  #pragma unroll
  for (int o = 32; o; o >>= 1) {
    kxx += __shfl_xor(kxx, o);
    kxy += __shfl_xor(kxy, o);
    kyy += __shfl_xor(kyy, o);
  }
  if (lane == 0) {
    bpart[gw] = kxx;
    bpart[2048 + gw] = kxy;
    bpart[4096 + gw] = kyy;
  }
}

// ---- stage A: per (chunk, slab) reduce: sum 64 slot-slabs, emit {sum^2, sum} ----
__global__ __launch_bounds__(256) void vdr_reduceA(const float* __restrict__ slabs,
                                                   double* __restrict__ partA) {
  const int j = blockIdx.y, tid = threadIdx.x;
  const int e = blockIdx.x * 256 + tid;
  const float* base = slabs + (size_t)j * SLAB + e;
  double s = 0.0;
  #pragma unroll
  for (int k = 0; k < 64; ++k) s += (double)base[(size_t)k * 4096];
  double sq = s * s, sm = s;
  #pragma unroll
  for (int o = 32; o; o >>= 1) { sq += __shfl_down(sq, o); sm += __shfl_down(sm, o); }
  __shared__ double sh[4][2];
  const int lane = tid & 63, wid = tid >> 6;
  if (lane == 0) { sh[wid][0] = sq; sh[wid][1] = sm; }
  __syncthreads();
  if (tid == 0) {
    partA[(size_t)(j * 16 + blockIdx.x) * 2 + 0] = sh[0][0] + sh[1][0] + sh[2][0] + sh[3][0];
    partA[(size_t)(j * 16 + blockIdx.x) * 2 + 1] = sh[0][1] + sh[1][1] + sh[2][1] + sh[3][1];
  }
}

// ---- stage B: combine partials + bpart, apply unbiased formula ----
__global__ __launch_bounds__(256) void vdr_reduceB(const double* __restrict__ partA,
                                                   const float* __restrict__ bpart,
                                                   float* __restrict__ out) {
  const int tid = threadIdx.x;
  __shared__ double ssq[4], ssum[4], s2sh[4][3];
  double s2[3] = {0.0, 0.0, 0.0};
  for (int i = tid; i < 2048; i += 256) {
    s2[0] += (double)bpart[i];
    s2[1] += (double)bpart[2048 + i];
    s2[2] += (double)bpart[4096 + i];
  }
  #pragma unroll
  for (int o = 32; o; o >>= 1) {
    s2[0] += __shfl_down(s2[0], o);
    s2[1] += __shfl_down(s2[1], o);
    s2[2] += __shfl_down(s2[2], o);
  }
  const int lane = tid & 63, wid = tid >> 6;
  if (lane == 0) { s2sh[wid][0] = s2[0]; s2sh[wid][1] = s2[1]; s2sh[wid][2] = s2[2]; }
  if (tid < 64) {
    const int j = tid >> 4, c = tid & 15;
    double sq = partA[(size_t)(j * 16 + c) * 2 + 0];
    double sm = partA[(size_t)(j * 16 + c) * 2 + 1];
    #pragma unroll
    for (int o = 8; o; o >>= 1) { sq += __shfl_down(sq, o, 16); sm += __shfl_down(sm, o, 16); }
    if (c == 0) { ssq[j] = sq; ssum[j] = sm; }
  }
  __syncthreads();
  if (tid == 0) {
    const double S2XX = s2sh[0][0] + s2sh[1][0] + s2sh[2][0] + s2sh[3][0];
    const double S2XY = s2sh[0][1] + s2sh[1][1] + s2sh[2][1] + s2sh[3][1];
    const double S2YY = s2sh[0][2] + s2sh[1][2] + s2sh[2][2] + s2sh[3][2];
    const double inv = 1.0 / 4096.0;
    const double r0 = S2XX - 2.0 * ssq[0] * inv + ssum[0] * ssum[0] * inv * inv;
    const double r1 = S2XY - ssq[1] * inv - ssq[2] * inv + ssum[1] * ssum[1] * inv * inv;
    const double r2 = S2YY - 2.0 * ssq[3] * inv + ssum[3] * ssum[3] * inv * inv;
    const double mf = 4096.0;
    out[0] = (float)((r0 - mf) / ((mf - 1.0) * mf)
                   + (r2 - mf) / ((mf - 1.0) * mf)
                   - 2.0 * r1 / (mf * mf));
  }
}

extern "C" void kernel_launch(void* const* d_in, const int* in_sizes, int n_in,
                              void* d_out, int out_size, void* d_ws, size_t ws_size,
                              hipStream_t stream) {
  const float* X1 = (const float*)d_in[0];
  const float* X2 = (const float*)d_in[1];
  char* ws = (char*)d_ws;
  float* sq1      = (float*)(ws + OFF_SQ1);
  float* sq2      = (float*)(ws + OFF_SQ2);
  _Float16* H1    = (_Float16*)(ws + OFF_H1);
  _Float16* H2    = (_Float16*)(ws + OFF_H2);
  float* slabs    = (float*)(ws + OFF_SLABS);
  float* bpart    = (float*)(ws + OFF_BPART);
  double* partA   = (double*)(ws + OFF_PARTA);

  vdr_prep<<<2048, 256, 0, stream>>>(X1, X2, H1, H2, sq1, sq2);
  vdr_main<<<512, 256, 0, stream>>>(H1, H2, sq1, sq2, slabs, bpart);
  dim3 ga(16, 4);
  vdr_reduceA<<<ga, 256, 0, stream>>>(slabs, partA);
  vdr_reduceB<<<1, 256, 0, stream>>>(partA, bpart, (float*)d_out);
}